// Round 5
// baseline (195.696 us; speedup 1.0000x reference)
//
#include <hip/hip_runtime.h>
#include <math.h>

#define B_ROWS 4096
#define D_DIM  1024
static constexpr float TEMP = 0.2f;

typedef __attribute__((ext_vector_type(8))) short bf16x8;  // 8 bf16 (4 VGPRs)
typedef __attribute__((ext_vector_type(4))) float f32x4;

// RNE float -> bf16 bits
__device__ inline unsigned short f2bf(float f) {
    unsigned int u = __float_as_uint(f);
    u += 0x7fffu + ((u >> 16) & 1u);
    return (unsigned short)(u >> 16);
}

// async global->LDS, 16 B/lane; LDS dest = wave-uniform base + lane*16
__device__ inline void gload_lds16(const unsigned short* g, unsigned short* l) {
    __builtin_amdgcn_global_load_lds(
        (const __attribute__((address_space(1))) unsigned int*)g,
        (__attribute__((address_space(3))) unsigned int*)l,
        16, 0, 0);
}

// ws layout: w[0]=pos acc (f32), w[1]=neg acc (f32), w[2]=grid-barrier ctr
// (u32), w[3]=finalize ticket (u32), then Zi (4096x1024 bf16) at w+16, Zj.

// ws is re-poisoned to 0xAA before every call: control words must be zeroed
// by a separate tiny dispatch before the fused kernel touches them.
__global__ void init_ctrl_kernel(float* __restrict__ w) {
    if (threadIdx.x < 2) w[threadIdx.x] = 0.0f;
    else if (threadIdx.x < 4) ((unsigned int*)w)[threadIdx.x] = 0u;
}

// ---------------------------------------------------------------------------
// Fused: phase 1 normalize+cast 16 rows/block -> grid barrier -> phase 2 GEMM
// (128x256 tile, BK=32, XOR-swizzled LDS, fused softplus epilogue).
// Grid MUST be 512 blocks: __launch_bounds__(256,2) caps combined VGPR+AGPR
// at 256/wave -> 2 blocks/CU -> all 512 co-resident (required by barrier).
// ---------------------------------------------------------------------------
__global__ __launch_bounds__(256, 2) void fused_simloss_kernel(
        const float* __restrict__ emb_i, const float* __restrict__ emb_j,
        unsigned short* Zi, unsigned short* Zj,
        float* w, float* out) {
    __shared__ __align__(16) unsigned short lA[128 * 32];  //  8 KB (Zj rows)
    __shared__ __align__(16) unsigned short lB[256 * 32];  // 16 KB (Zi rows)
    __shared__ float rn[4], rp[4];

    const int tid  = threadIdx.x;
    const int lane = tid & 63;
    const int wave = tid >> 6;
    const int bid  = blockIdx.y * gridDim.x + blockIdx.x;
    const unsigned int nblk = gridDim.x * gridDim.y;

    // ---- phase 1: normalize + cast rows [bid*16, bid*16+16) ----
    #pragma unroll
    for (int it = 0; it < 4; ++it) {
        const int row = bid * 16 + it * 4 + wave;          // 0..8191
        const float* src; unsigned short* dst; int r;
        if (row < B_ROWS) { src = emb_i; dst = Zi; r = row; }
        else              { src = emb_j; dst = Zj; r = row - B_ROWS; }

        const float4* p = (const float4*)(src + (size_t)r * D_DIM);
        float4 v0 = p[lane], v1 = p[64 + lane], v2 = p[128 + lane], v3 = p[192 + lane];
        float s = v0.x*v0.x + v0.y*v0.y + v0.z*v0.z + v0.w*v0.w
                + v1.x*v1.x + v1.y*v1.y + v1.z*v1.z + v1.w*v1.w
                + v2.x*v2.x + v2.y*v2.y + v2.z*v2.z + v2.w*v2.w
                + v3.x*v3.x + v3.y*v3.y + v3.z*v3.z + v3.w*v3.w;
        #pragma unroll
        for (int m = 1; m < 64; m <<= 1) s += __shfl_xor(s, m, 64);
        const float inv = 1.0f / fmaxf(sqrtf(s), 1e-12f);

        ushort4* q = (ushort4*)(dst + (size_t)r * D_DIM);
        ushort4 o0 = { f2bf(v0.x*inv), f2bf(v0.y*inv), f2bf(v0.z*inv), f2bf(v0.w*inv) };
        ushort4 o1 = { f2bf(v1.x*inv), f2bf(v1.y*inv), f2bf(v1.z*inv), f2bf(v1.w*inv) };
        ushort4 o2 = { f2bf(v2.x*inv), f2bf(v2.y*inv), f2bf(v2.z*inv), f2bf(v2.w*inv) };
        ushort4 o3 = { f2bf(v3.x*inv), f2bf(v3.y*inv), f2bf(v3.z*inv), f2bf(v3.w*inv) };
        q[lane] = o0; q[64 + lane] = o1; q[128 + lane] = o2; q[192 + lane] = o3;
    }

    // ---- grid barrier (all 512 blocks co-resident by construction) ----
    __syncthreads();                 // all waves' stores drained (vmcnt) & done
    unsigned int* ctr = (unsigned int*)w + 2;
    if (tid == 0) {
        __threadfence();             // agent release: write-back L2 (cross-XCD)
        __hip_atomic_fetch_add(ctr, 1u, __ATOMIC_RELEASE, __HIP_MEMORY_SCOPE_AGENT);
        while (__hip_atomic_load(ctr, __ATOMIC_ACQUIRE, __HIP_MEMORY_SCOPE_AGENT) < nblk)
            __builtin_amdgcn_s_sleep(8);
        __threadfence();             // agent acquire: invalidate local L2
    }
    __syncthreads();

    // ---- phase 2: GEMM, 128x256 tile, BK=32 (identical to R4) ----
    const int wy = wave >> 1, wx = wave & 1;
    const int rowBase = blockIdx.y * 128;   // a (Zj rows)
    const int colBase = blockIdx.x * 256;   // b (Zi rows)

    // staging: chunk = 16 rows x 64 B = 1 KB; XOR swizzle piece p=(c+(R>>1))&3
    const int lrow = lane >> 2;             // 0..15 row within chunk
    const int lp   = lane & 3;              // physical 16B piece
    const int lc   = (lp - (lrow >> 1)) & 3;  // logical k-chunk (swizzle^-1)
    const unsigned short* gA0 = Zj + (size_t)(rowBase + (2*wave+0)*16 + lrow) * D_DIM + lc*8;
    const unsigned short* gA1 = Zj + (size_t)(rowBase + (2*wave+1)*16 + lrow) * D_DIM + lc*8;
    const unsigned short* gB0 = Zi + (size_t)(colBase + (4*wave+0)*16 + lrow) * D_DIM + lc*8;
    const unsigned short* gB1 = Zi + (size_t)(colBase + (4*wave+1)*16 + lrow) * D_DIM + lc*8;
    const unsigned short* gB2 = Zi + (size_t)(colBase + (4*wave+2)*16 + lrow) * D_DIM + lc*8;
    const unsigned short* gB3 = Zi + (size_t)(colBase + (4*wave+3)*16 + lrow) * D_DIM + lc*8;
    unsigned short* sA0 = lA + (2*wave+0) * 512;
    unsigned short* sA1 = lA + (2*wave+1) * 512;
    unsigned short* sB0 = lB + (4*wave+0) * 512;
    unsigned short* sB1 = lB + (4*wave+1) * 512;
    unsigned short* sB2 = lB + (4*wave+2) * 512;
    unsigned short* sB3 = lB + (4*wave+3) * 512;

    const int fr = lane & 15;
    const int q4 = lane >> 4;
    const int p0 = (q4 + (fr >> 1)) & 3;
    const unsigned short* fA = lA + (wy * 64 + fr) * 32 + p0 * 8;
    const unsigned short* fB = lB + (wx * 128 + fr) * 32 + p0 * 8;

    f32x4 acc[4][8];
    #pragma unroll
    for (int i = 0; i < 4; ++i)
        #pragma unroll
        for (int j = 0; j < 8; ++j)
            acc[i][j] = (f32x4){0.f, 0.f, 0.f, 0.f};

    for (int k0 = 0; k0 < D_DIM; k0 += 32) {
        __syncthreads();                    // prior readers done
        gload_lds16(gA0, sA0); gload_lds16(gA1, sA1);
        gload_lds16(gB0, sB0); gload_lds16(gB1, sB1);
        gload_lds16(gB2, sB2); gload_lds16(gB3, sB3);
        gA0 += 32; gA1 += 32; gB0 += 32; gB1 += 32; gB2 += 32; gB3 += 32;
        __syncthreads();                    // staging visible

        bf16x8 a[4], b[8];
        #pragma unroll
        for (int i = 0; i < 4; ++i) a[i] = *(const bf16x8*)(fA + i * 16 * 32);
        #pragma unroll
        for (int j = 0; j < 8; ++j) b[j] = *(const bf16x8*)(fB + j * 16 * 32);
        #pragma unroll
        for (int i = 0; i < 4; ++i)
            #pragma unroll
            for (int j = 0; j < 8; ++j)
                acc[i][j] = __builtin_amdgcn_mfma_f32_16x16x32_bf16(
                    a[i], b[j], acc[i][j], 0, 0, 0);
    }

    // fused epilogue; C layout: row=(lane>>4)*4+r, col=lane&15
    const int cr = q4 * 4;
    const int cc = lane & 15;
    float neg = 0.f, pos = 0.f;
    #pragma unroll
    for (int i = 0; i < 4; ++i) {
        const int abase = rowBase + wy * 64 + i * 16 + cr;
        #pragma unroll
        for (int j = 0; j < 8; ++j) {
            const int b = colBase + wx * 128 + j * 16 + cc;
            #pragma unroll
            for (int r = 0; r < 4; ++r) {
                const float x = acc[i][j][r] - TEMP;   // sim - T
                if (abase + r == b) pos += __logf(1.0f + __expf(-x));
                else                neg += __logf(1.0f + __expf(x));
            }
        }
    }
    #pragma unroll
    for (int off = 32; off > 0; off >>= 1) {
        neg += __shfl_down(neg, off, 64);
        pos += __shfl_down(pos, off, 64);
    }
    if (lane == 0) { rn[wave] = neg; rp[wave] = pos; }
    __syncthreads();
    if (tid == 0) {
        atomicAdd(&w[1], rn[0] + rn[1] + rn[2] + rn[3]);
        if ((int)blockIdx.x == (int)(blockIdx.y >> 1))   // tile holding diagonal
            atomicAdd(&w[0], rp[0] + rp[1] + rp[2] + rp[3]);
        __threadfence();
        unsigned int done = atomicAdd(((unsigned int*)w) + 3, 1u);
        if (done == nblk - 1) {                          // last block finalizes
            const float psum = atomicAdd(&w[0], 0.0f);
            const float nsum = atomicAdd(&w[1], 0.0f);
            out[0] = 0.5f * (psum / (float)B_ROWS)
                   + 0.5f * (nsum / ((float)B_ROWS * (float)(B_ROWS - 1)));
        }
    }
}

extern "C" void kernel_launch(void* const* d_in, const int* in_sizes, int n_in,
                              void* d_out, int out_size, void* d_ws, size_t ws_size,
                              hipStream_t stream) {
    const float* emb_i = (const float*)d_in[0];
    const float* emb_j = (const float*)d_in[1];
    float* w = (float*)d_ws;
    unsigned short* Zi = (unsigned short*)(w + 16);
    unsigned short* Zj = Zi + (size_t)B_ROWS * D_DIM;
    float* out = (float*)d_out;

    init_ctrl_kernel<<<1, 64, 0, stream>>>(w);
    dim3 grid(B_ROWS / 256, B_ROWS / 128);   // 16 x 32 = 512 blocks = 2/CU
    fused_simloss_kernel<<<grid, 256, 0, stream>>>(emb_i, emb_j, Zi, Zj, w, out);
}

// Round 6
// 117.913 us; speedup vs baseline: 1.6597x; 1.6597x over previous
//
#include <hip/hip_runtime.h>
#include <math.h>

#define B_ROWS 4096
#define D_DIM  1024
static constexpr float TEMP = 0.2f;
static constexpr float FP8_SCALE = 16.0f;        // per-side scale before cast
static constexpr float INV_S2 = 1.0f / 256.0f;   // 1/SCALE^2: acc -> sim

typedef __attribute__((ext_vector_type(4))) float f32x4;

// float -> OCP e4m3fn byte, RNE. Data path: |f| <= ~4, no NaN/inf.
__device__ inline unsigned char f2fp8(float f) {
    unsigned int u = __float_as_uint(f);
    unsigned int s = (u >> 24) & 0x80u;
    float af = fabsf(f);
    unsigned char b;
    if (af >= 0x1.0p-6f) {                 // normal e4m3 range
        unsigned int au = u & 0x7fffffffu;
        unsigned int lsb = (au >> 20) & 1u;
        au += 0x7ffffu + lsb;              // RNE into 3 mantissa bits
        int e = (int)(au >> 23) - 127 + 7;
        unsigned int m = (au >> 20) & 7u;
        if (e > 15 || (e == 15 && m > 6)) b = 0x7e;   // saturate 448
        else b = (unsigned char)((e << 3) | m);
    } else {                               // subnormal: quantum 2^-9
        int q = (int)rintf(af * 512.0f);
        b = (unsigned char)(q >= 8 ? 0x08 : q);
    }
    return (unsigned char)(b | s);
}

__device__ inline unsigned int f2fp8x4(float4 v) {
    return (unsigned int)f2fp8(v.x)
         | ((unsigned int)f2fp8(v.y) << 8)
         | ((unsigned int)f2fp8(v.z) << 16)
         | ((unsigned int)f2fp8(v.w) << 24);
}

// async global->LDS, 16 B/lane; LDS dest = wave-uniform base + lane*16
__device__ inline void gload_lds16(const unsigned char* g, unsigned char* l) {
    __builtin_amdgcn_global_load_lds(
        (const __attribute__((address_space(1))) unsigned int*)g,
        (__attribute__((address_space(3))) unsigned int*)l,
        16, 0, 0);
}

// ws layout: w[0]=pos acc, w[1]=neg acc, w[2]=finalize ticket (u32),
//            then Zi8 (4096x1024 fp8) at byte (w+16), Zj8 after.

// Wave-per-row normalize (fp32) + scale by 16 + cast to fp8 e4m3.
// Block 0 thread 0 zeroes control words (done before gemm launches).
__global__ __launch_bounds__(256) void norm_cast_kernel(
        const float* __restrict__ emb_i, const float* __restrict__ emb_j,
        unsigned char* __restrict__ Zi8, unsigned char* __restrict__ Zj8,
        float* __restrict__ w) {
    const int tid = threadIdx.x;
    if (blockIdx.x == 0 && tid == 0) {
        w[0] = 0.0f; w[1] = 0.0f;
        ((unsigned int*)w)[2] = 0u;
    }
    const int wave = tid >> 6, lane = tid & 63;
    const int row = blockIdx.x * 4 + wave;          // 0..8191
    const float* src; unsigned char* dst; int r;
    if (row < B_ROWS) { src = emb_i; dst = Zi8; r = row; }
    else              { src = emb_j; dst = Zj8; r = row - B_ROWS; }

    const float4* p = (const float4*)(src + (size_t)r * D_DIM);
    float4 v0 = p[lane], v1 = p[64 + lane], v2 = p[128 + lane], v3 = p[192 + lane];
    float s = v0.x*v0.x + v0.y*v0.y + v0.z*v0.z + v0.w*v0.w
            + v1.x*v1.x + v1.y*v1.y + v1.z*v1.z + v1.w*v1.w
            + v2.x*v2.x + v2.y*v2.y + v2.z*v2.z + v2.w*v2.w
            + v3.x*v3.x + v3.y*v3.y + v3.z*v3.z + v3.w*v3.w;
    #pragma unroll
    for (int m = 1; m < 64; m <<= 1) s += __shfl_xor(s, m, 64);
    const float inv = FP8_SCALE / fmaxf(sqrtf(s), 1e-12f);

    float4 a0 = {v0.x*inv, v0.y*inv, v0.z*inv, v0.w*inv};
    float4 a1 = {v1.x*inv, v1.y*inv, v1.z*inv, v1.w*inv};
    float4 a2 = {v2.x*inv, v2.y*inv, v2.z*inv, v2.w*inv};
    float4 a3 = {v3.x*inv, v3.y*inv, v3.z*inv, v3.w*inv};
    unsigned int* q = (unsigned int*)(dst + (size_t)r * D_DIM);
    q[lane]       = f2fp8x4(a0);
    q[64 + lane]  = f2fp8x4(a1);
    q[128 + lane] = f2fp8x4(a2);
    q[192 + lane] = f2fp8x4(a3);
}

// 128x256 block tile, BK=64 (fp8: 64 B/row), 4 waves: wave (wy,wx) owns
// 64x128 = 4x8 MFMA tiles of 16x16x32 fp8_fp8, two K-halves per iter.
// Grid 16x32 = 512 blocks = exactly 2 resident/CU.
//
// LDS: row = 64 B = 4 x 16B pieces. XOR swizzle: logical piece c of row r
// sits at physical piece p = (c + (r>>2)) & 3  (r = row mod 16).
// global_load_lds writes lane*16, so staging fetches the swizzled *global*
// 16B piece. Fragment b64 reads then cover every bank exactly 4x (uniform).
__global__ __launch_bounds__(256, 2) void simloss_mfma_fp8_kernel(
        const unsigned char* __restrict__ Zi8,
        const unsigned char* __restrict__ Zj8,
        float* __restrict__ w, float* __restrict__ out) {
    __shared__ __align__(16) unsigned char lA[128 * 64];  //  8 KB (Zj rows)
    __shared__ __align__(16) unsigned char lB[256 * 64];  // 16 KB (Zi rows)
    __shared__ float rn[4], rp[4];

    const int tid  = threadIdx.x;
    const int lane = tid & 63;
    const int wave = tid >> 6;
    const int wy = wave >> 1, wx = wave & 1;
    const int rowBase = blockIdx.y * 128;   // a (Zj rows)
    const int colBase = blockIdx.x * 256;   // b (Zi rows)

    // --- staging: chunk = 16 rows x 64 B = 1 KB. A: 8 chunks (wave owns 2),
    //     B: 16 chunks (wave owns 4). Lane: row lr = lane>>2, piece lp = lane&3.
    const int lrow = lane >> 2;               // 0..15
    const int lp   = lane & 3;                // physical 16B piece
    const int lc   = (lp - (lrow >> 2)) & 3;  // logical piece (swizzle^-1)
    const unsigned char* gA0 = Zj8 + (size_t)(rowBase + (2*wave+0)*16 + lrow) * D_DIM + lc*16;
    const unsigned char* gA1 = Zj8 + (size_t)(rowBase + (2*wave+1)*16 + lrow) * D_DIM + lc*16;
    const unsigned char* gB0 = Zi8 + (size_t)(colBase + (4*wave+0)*16 + lrow) * D_DIM + lc*16;
    const unsigned char* gB1 = Zi8 + (size_t)(colBase + (4*wave+1)*16 + lrow) * D_DIM + lc*16;
    const unsigned char* gB2 = Zi8 + (size_t)(colBase + (4*wave+2)*16 + lrow) * D_DIM + lc*16;
    const unsigned char* gB3 = Zi8 + (size_t)(colBase + (4*wave+3)*16 + lrow) * D_DIM + lc*16;
    unsigned char* sA0 = lA + (2*wave+0) * 1024;
    unsigned char* sA1 = lA + (2*wave+1) * 1024;
    unsigned char* sB0 = lB + (4*wave+0) * 1024;
    unsigned char* sB1 = lB + (4*wave+1) * 1024;
    unsigned char* sB2 = lB + (4*wave+2) * 1024;
    unsigned char* sB3 = lB + (4*wave+3) * 1024;

    // --- fragment addressing: lane needs k = h*32 + q*8 + j  (8 B = b64).
    //     logical piece = 2h + (q>>1); physical = (that + (fr>>2)) & 3.
    const int fr = lane & 15;
    const int q4 = lane >> 4;            // 0..3
    const int qh = q4 >> 1, qb = q4 & 1;
    const int P0 = (qh + 0 + (fr >> 2)) & 3;      // k-half 0
    const int P1 = (qh + 2 + (fr >> 2)) & 3;      // k-half 1
    const unsigned char* fA0 = lA + (wy * 64 + fr) * 64 + P0 * 16 + qb * 8;
    const unsigned char* fA1 = lA + (wy * 64 + fr) * 64 + P1 * 16 + qb * 8;
    const unsigned char* fB0 = lB + (wx * 128 + fr) * 64 + P0 * 16 + qb * 8;
    const unsigned char* fB1 = lB + (wx * 128 + fr) * 64 + P1 * 16 + qb * 8;

    f32x4 acc[4][8];
    #pragma unroll
    for (int i = 0; i < 4; ++i)
        #pragma unroll
        for (int j = 0; j < 8; ++j)
            acc[i][j] = (f32x4){0.f, 0.f, 0.f, 0.f};

    for (int k0 = 0; k0 < D_DIM; k0 += 64) {
        __syncthreads();                    // prior readers done
        gload_lds16(gA0, sA0); gload_lds16(gA1, sA1);
        gload_lds16(gB0, sB0); gload_lds16(gB1, sB1);
        gload_lds16(gB2, sB2); gload_lds16(gB3, sB3);
        gA0 += 64; gA1 += 64; gB0 += 64; gB1 += 64; gB2 += 64; gB3 += 64;
        __syncthreads();                    // staging visible

        // k-half 0
        {
            long a[4], b[8];
            #pragma unroll
            for (int i = 0; i < 4; ++i) a[i] = *(const long*)(fA0 + i * 1024);
            #pragma unroll
            for (int j = 0; j < 8; ++j) b[j] = *(const long*)(fB0 + j * 1024);
            #pragma unroll
            for (int i = 0; i < 4; ++i)
                #pragma unroll
                for (int j = 0; j < 8; ++j)
                    acc[i][j] = __builtin_amdgcn_mfma_f32_16x16x32_fp8_fp8(
                        a[i], b[j], acc[i][j], 0, 0, 0);
        }
        // k-half 1
        {
            long a[4], b[8];
            #pragma unroll
            for (int i = 0; i < 4; ++i) a[i] = *(const long*)(fA1 + i * 1024);
            #pragma unroll
            for (int j = 0; j < 8; ++j) b[j] = *(const long*)(fB1 + j * 1024);
            #pragma unroll
            for (int i = 0; i < 4; ++i)
                #pragma unroll
                for (int j = 0; j < 8; ++j)
                    acc[i][j] = __builtin_amdgcn_mfma_f32_16x16x32_fp8_fp8(
                        a[i], b[j], acc[i][j], 0, 0, 0);
        }
    }

    // --- fused epilogue; C layout: row=(lane>>4)*4+r, col=lane&15
    const int cr = q4 * 4;
    const int cc = lane & 15;
    float neg = 0.f, pos = 0.f;
    #pragma unroll
    for (int i = 0; i < 4; ++i) {
        const int abase = rowBase + wy * 64 + i * 16 + cr;
        #pragma unroll
        for (int j = 0; j < 8; ++j) {
            const int b = colBase + wx * 128 + j * 16 + cc;
            #pragma unroll
            for (int r = 0; r < 4; ++r) {
                const float x = acc[i][j][r] * INV_S2 - TEMP;   // sim - T
                if (abase + r == b) pos += __logf(1.0f + __expf(-x));
                else                neg += __logf(1.0f + __expf(x));
            }
        }
    }
    #pragma unroll
    for (int off = 32; off > 0; off >>= 1) {
        neg += __shfl_down(neg, off, 64);
        pos += __shfl_down(pos, off, 64);
    }
    if (lane == 0) { rn[wave] = neg; rp[wave] = pos; }
    __syncthreads();
    if (tid == 0) {
        atomicAdd(&w[1], rn[0] + rn[1] + rn[2] + rn[3]);
        if ((int)blockIdx.x == (int)(blockIdx.y >> 1))   // tile holding diagonal
            atomicAdd(&w[0], rp[0] + rp[1] + rp[2] + rp[3]);
        __threadfence();
        unsigned int done = atomicAdd(((unsigned int*)w) + 2, 1u);
        if (done == gridDim.x * gridDim.y - 1) {         // last block finalizes
            const float psum = atomicAdd(&w[0], 0.0f);
            const float nsum = atomicAdd(&w[1], 0.0f);
            out[0] = 0.5f * (psum / (float)B_ROWS)
                   + 0.5f * (nsum / ((float)B_ROWS * (float)(B_ROWS - 1)));
        }
    }
}

extern "C" void kernel_launch(void* const* d_in, const int* in_sizes, int n_in,
                              void* d_out, int out_size, void* d_ws, size_t ws_size,
                              hipStream_t stream) {
    const float* emb_i = (const float*)d_in[0];
    const float* emb_j = (const float*)d_in[1];
    float* w = (float*)d_ws;
    unsigned char* Zi8 = (unsigned char*)(w + 16);
    unsigned char* Zj8 = Zi8 + (size_t)B_ROWS * D_DIM;
    float* out = (float*)d_out;

    norm_cast_kernel<<<2 * B_ROWS / 4, 256, 0, stream>>>(emb_i, emb_j, Zi8, Zj8, w);
    dim3 grid(B_ROWS / 256, B_ROWS / 128);   // 16 x 32 = 512 blocks, 2/CU
    simloss_mfma_fp8_kernel<<<grid, 256, 0, stream>>>(Zi8, Zj8, w, out);
}